// Round 2
// baseline (303.634 us; speedup 1.0000x reference)
//
#include <hip/hip_runtime.h>
#include <hip/hip_bf16.h>
#include <string.h>

#define GAMMA 0.015625f
#define D 64

typedef short bf16x8 __attribute__((ext_vector_type(8)));   // 8 bf16 = 4 VGPRs
typedef float floatx4 __attribute__((ext_vector_type(4)));

// Convert 8 contiguous fp32 -> bf16x8 fragment (RNE), accumulating the sum of
// squares of the ROUNDED values into ss (so d2 = xsq+ysq-2*cross is the exact
// squared distance of the bf16 vectors, >= 0 up to fp32 roundoff).
__device__ __forceinline__ bf16x8 cvt8(const float* __restrict__ p, float& ss) {
    const float4 a = *(const float4*)p;
    const float4 b = *(const float4*)(p + 4);
    const float f[8] = {a.x, a.y, a.z, a.w, b.x, b.y, b.z, b.w};
    bf16x8 r;
#pragma unroll
    for (int i = 0; i < 8; ++i) {
        __hip_bfloat16 h = __float2bfloat16(f[i]);
        short s;
        memcpy(&s, &h, sizeof(short));
        r[i] = s;
        const float bv = __bfloat162float(h);
        ss = fmaf(bv, bv, ss);
    }
    return r;
}

// ---------------------------------------------------------------------------
// Fully fused RBF kernel matrix: 128x128 block tile, 4 waves in 2x2, each
// wave owns a 64x64 output sub-tile.
//
// Fragments are loaded straight from the fp32 inputs (row-major, K=64
// contiguous) and converted to bf16 in registers: for mfma_f32_16x16x32_bf16
// lane (quad,l16) holds A[m = l16][k = quad*8 + j] -> two aligned float4
// loads. B = sv^T so B[k][n] = sv[n][k]: identical row-load pattern.
// Row norms of the rounded values are built in-register: per-lane partial
// (16 elements) + shfl_xor across the 4 quads.
// C/D layout: col = lane&15, row = quad*4 + reg.
// ---------------------------------------------------------------------------
__global__ __launch_bounds__(256) void rbf_fused(const float* __restrict__ A,
                                                 const float* __restrict__ B,
                                                 float* __restrict__ out,
                                                 int M) {
    const int wid  = threadIdx.x >> 6;
    const int lane = threadIdx.x & 63;
    const int quad = lane >> 4;
    const int l16  = lane & 15;

    const long row0 = (long)blockIdx.y * 128 + (wid >> 1) * 64;
    const long col0 = (long)blockIdx.x * 128 + (wid & 1) * 64;

    bf16x8 af[4][2], bfr[4][2];
    float xnorm[4];   // norm of A row (mb*16 + l16), replicated across quads
    float ynorm[4];   // norm of B row (nb*16 + l16), replicated across quads

#pragma unroll
    for (int mb = 0; mb < 4; ++mb) {
        const float* p = A + (row0 + mb * 16 + l16) * D + quad * 8;
        float s = 0.f;
        af[mb][0] = cvt8(p, s);        // k = quad*8 + [0,8)
        af[mb][1] = cvt8(p + 32, s);   // k = 32 + quad*8 + [0,8)
        s += __shfl_xor(s, 16, 64);
        s += __shfl_xor(s, 32, 64);
        xnorm[mb] = s;
    }
#pragma unroll
    for (int nb = 0; nb < 4; ++nb) {
        const float* p = B + (col0 + nb * 16 + l16) * D + quad * 8;
        float s = 0.f;
        bfr[nb][0] = cvt8(p, s);
        bfr[nb][1] = cvt8(p + 32, s);
        s += __shfl_xor(s, 16, 64);
        s += __shfl_xor(s, 32, 64);
        ynorm[nb] = s;
    }

    floatx4 acc[4][4];
#pragma unroll
    for (int mb = 0; mb < 4; ++mb)
#pragma unroll
        for (int nb = 0; nb < 4; ++nb)
            acc[mb][nb] = (floatx4){0.f, 0.f, 0.f, 0.f};

#pragma unroll
    for (int k = 0; k < 2; ++k)
#pragma unroll
        for (int mb = 0; mb < 4; ++mb)
#pragma unroll
            for (int nb = 0; nb < 4; ++nb)
                acc[mb][nb] = __builtin_amdgcn_mfma_f32_16x16x32_bf16(
                    af[mb][k], bfr[nb][k], acc[mb][nb], 0, 0, 0);

    // Epilogue: d2 = xsq + ysq - 2*cross, clamped; out = exp(-gamma*d2).
    // C-layout rows for this lane are quad*4 + r; their norms live in the
    // lanes with l16 == quad*4 + r -> one shuffle each.
#pragma unroll
    for (int mb = 0; mb < 4; ++mb) {
        float xn[4];
#pragma unroll
        for (int r = 0; r < 4; ++r)
            xn[r] = __shfl(xnorm[mb], quad * 4 + r, 64);
#pragma unroll
        for (int nb = 0; nb < 4; ++nb) {
            const long col = col0 + nb * 16 + l16;
            const float yn = ynorm[nb];
#pragma unroll
            for (int r = 0; r < 4; ++r) {
                const long row = row0 + mb * 16 + quad * 4 + r;
                float d2 = fmaxf(xn[r] + yn - 2.0f * acc[mb][nb][r], 0.0f);
                out[row * (long)M + col] = __expf(-GAMMA * d2);
            }
        }
    }
}

// ---------------------------------------------------------------------------
// Fallback (dims not a multiple of 128): direct fp32 distance, correct.
// ---------------------------------------------------------------------------
__global__ __launch_bounds__(256) void rbf_naive(const float* __restrict__ X,
                                                 const float* __restrict__ Y,
                                                 float* __restrict__ out,
                                                 int N, int M) {
    long idx = (long)blockIdx.x * blockDim.x + threadIdx.x;
    if (idx >= (long)N * M) return;
    long i = idx / M, j = idx % M;
    float s = 0.0f;
#pragma unroll
    for (int k = 0; k < D; ++k) {
        float d = X[i * D + k] - Y[j * D + k];
        s = fmaf(d, d, s);
    }
    out[idx] = __expf(-GAMMA * s);
}

extern "C" void kernel_launch(void* const* d_in, const int* in_sizes, int n_in,
                              void* d_out, int out_size, void* d_ws, size_t ws_size,
                              hipStream_t stream) {
    const float* data = (const float*)d_in[0];
    const float* sv   = (const float*)d_in[1];
    float* out = (float*)d_out;
    // NOTE: in_sizes is in ELEMENTS (fp32 count), not bytes: 8192*64 = 524288.
    const int N = in_sizes[0] / D;   // rows of data
    const int M = in_sizes[1] / D;   // rows of sv

    if ((N % 128) == 0 && (M % 128) == 0) {
        dim3 grid(M / 128, N / 128);
        hipLaunchKernelGGL(rbf_fused, grid, dim3(256), 0, stream,
                           data, sv, out, M);
    } else {
        long total = (long)N * M;
        long blocks = (total + 255) / 256;
        hipLaunchKernelGGL(rbf_naive, dim3((unsigned)blocks), dim3(256), 0, stream,
                           data, sv, out, N, M);
    }
}

// Round 4
// 300.339 us; speedup vs baseline: 1.0110x; 1.0110x over previous
//
#include <hip/hip_runtime.h>
#include <hip/hip_bf16.h>
#include <string.h>

#define GAMMA 0.015625f
#define D 64
#define CT 4   // column tiles (128 cols each) per block

typedef short bf16x8 __attribute__((ext_vector_type(8)));   // 8 bf16 = 4 VGPRs
typedef float floatx16 __attribute__((ext_vector_type(16)));

// Convert 8 contiguous fp32 -> bf16x8 fragment (RNE), accumulating the sum of
// squares of the ROUNDED values into ss (so d2 = xsq+ysq-2*cross is the exact
// squared distance of the bf16 vectors, >= 0 up to fp32 roundoff).
__device__ __forceinline__ bf16x8 cvt8(const float* __restrict__ p, float& ss) {
    const float4 a = *(const float4*)p;
    const float4 b = *(const float4*)(p + 4);
    const float f[8] = {a.x, a.y, a.z, a.w, b.x, b.y, b.z, b.w};
    bf16x8 r;
#pragma unroll
    for (int i = 0; i < 8; ++i) {
        __hip_bfloat16 h = __float2bfloat16(f[i]);
        short s;
        memcpy(&s, &h, sizeof(short));
        r[i] = s;
        const float bv = __bfloat162float(h);
        ss = fmaf(bv, bv, ss);
    }
    return r;
}

// ---------------------------------------------------------------------------
// Fused RBF kernel matrix, 32x32x16 MFMA variant.
//
// Block = 128 rows x 512 cols (CT=4 tiles of 128), 4 waves in 2x2 per tile;
// each wave owns a 64x64 sub-tile = 2x2 of 32x32 MFMAs, K=64 in 4 steps.
//
// A/B fragment (mfma_f32_32x32x16_bf16): lane holds row/col = lane&31,
// k = (lane>>5)*8 + j  -> 8 contiguous k -> straight fp32 loads + in-reg cvt.
// A fragments + row norms are loaded ONCE per block and reused for CT tiles.
// C/D layout (measured): col = lane&31, row = (reg&3) + 8*(reg>>2) + 4*(lane>>5)
// -> every store instruction writes 2 full aligned 128B lines.
// B-row norm is lane-local in the epilogue (col == lane&31 == norm home lane).
// ---------------------------------------------------------------------------
__global__ __launch_bounds__(256) void rbf_fused32(const float* __restrict__ A,
                                                   const float* __restrict__ B,
                                                   float* __restrict__ out,
                                                   int M) {
    const int wid  = threadIdx.x >> 6;
    const int lane = threadIdx.x & 63;
    const int r32  = lane & 31;
    const int h    = lane >> 5;

    const long row0 = (long)blockIdx.y * 128 + (wid >> 1) * 64;
    const long colW = (long)blockIdx.x * (128 * CT) + (wid & 1) * 64;

    // ---- A fragments + row norms (once per block, reused for CT tiles)
    bf16x8 af[2][4];
    float xnorm[2];   // norm of A row (mb*32 + r32), replicated across h
#pragma unroll
    for (int mb = 0; mb < 2; ++mb) {
        const float* p = A + (row0 + mb * 32 + r32) * D + h * 8;
        float s = 0.f;
#pragma unroll
        for (int ks = 0; ks < 4; ++ks)
            af[mb][ks] = cvt8(p + ks * 16, s);   // k = ks*16 + h*8 + [0,8)
        s += __shfl_xor(s, 32, 64);
        xnorm[mb] = s;
    }

    for (int ct = 0; ct < CT; ++ct) {
        const long colT = colW + (long)ct * 128;

        // ---- B fragments + col norms for this tile
        bf16x8 bfr[2][4];
        float ynorm[2];
#pragma unroll
        for (int nb = 0; nb < 2; ++nb) {
            const float* p = B + (colT + nb * 32 + r32) * D + h * 8;
            float s = 0.f;
#pragma unroll
            for (int ks = 0; ks < 4; ++ks)
                bfr[nb][ks] = cvt8(p + ks * 16, s);
            s += __shfl_xor(s, 32, 64);
            ynorm[nb] = s;
        }

        floatx16 acc[2][2] = {};
#pragma unroll
        for (int ks = 0; ks < 4; ++ks)
#pragma unroll
            for (int mb = 0; mb < 2; ++mb)
#pragma unroll
                for (int nb = 0; nb < 2; ++nb)
                    acc[mb][nb] = __builtin_amdgcn_mfma_f32_32x32x16_bf16(
                        af[mb][ks], bfr[nb][ks], acc[mb][nb], 0, 0, 0);

        // ---- Epilogue: d2 = xsq+ysq-2*cross (clamped), out = exp(-gamma*d2)
#pragma unroll
        for (int mb = 0; mb < 2; ++mb) {
            float xnv[16];
#pragma unroll
            for (int rg = 0; rg < 16; ++rg)
                xnv[rg] = __shfl(xnorm[mb], (rg & 3) + 8 * (rg >> 2) + 4 * h, 64);
#pragma unroll
            for (int nb = 0; nb < 2; ++nb) {
                const long col = colT + nb * 32 + r32;
                const float yn = ynorm[nb];
                float* op = out + (row0 + mb * 32) * (long)M + col;
#pragma unroll
                for (int rg = 0; rg < 16; ++rg) {
                    const int rl = (rg & 3) + 8 * (rg >> 2) + 4 * h;
                    float d2 = fmaxf(xnv[rg] + yn - 2.0f * acc[mb][nb][rg], 0.0f);
                    op[(long)rl * M] = __expf(-GAMMA * d2);
                }
            }
        }
    }
}

// ---------------------------------------------------------------------------
// Fallback (dims not multiples of the tile): direct fp32 distance, correct.
// ---------------------------------------------------------------------------
__global__ __launch_bounds__(256) void rbf_naive(const float* __restrict__ X,
                                                 const float* __restrict__ Y,
                                                 float* __restrict__ out,
                                                 int N, int M) {
    long idx = (long)blockIdx.x * blockDim.x + threadIdx.x;
    if (idx >= (long)N * M) return;
    long i = idx / M, j = idx % M;
    float s = 0.0f;
#pragma unroll
    for (int k = 0; k < D; ++k) {
        float d = X[i * D + k] - Y[j * D + k];
        s = fmaf(d, d, s);
    }
    out[idx] = __expf(-GAMMA * s);
}

extern "C" void kernel_launch(void* const* d_in, const int* in_sizes, int n_in,
                              void* d_out, int out_size, void* d_ws, size_t ws_size,
                              hipStream_t stream) {
    const float* data = (const float*)d_in[0];
    const float* sv   = (const float*)d_in[1];
    float* out = (float*)d_out;
    // NOTE: in_sizes is in ELEMENTS (fp32 count), not bytes: 8192*64 = 524288.
    const int N = in_sizes[0] / D;   // rows of data
    const int M = in_sizes[1] / D;   // rows of sv

    if ((N % 128) == 0 && (M % (128 * CT)) == 0) {
        dim3 grid(M / (128 * CT), N / 128);
        hipLaunchKernelGGL(rbf_fused32, grid, dim3(256), 0, stream,
                           data, sv, out, M);
    } else {
        long total = (long)N * M;
        long blocks = (total + 255) / 256;
        hipLaunchKernelGGL(rbf_naive, dim3((unsigned)blocks), dim3(256), 0, stream,
                           data, sv, out, N, M);
    }
}

// Round 5
// 272.741 us; speedup vs baseline: 1.1133x; 1.1012x over previous
//
#include <hip/hip_runtime.h>
#include <hip/hip_bf16.h>
#include <string.h>

#define GAMMA 0.015625f
#define D 64
#define CT 2   // column tiles (128 cols) per GEMM block: block = 128 x 256

typedef short bf16x8 __attribute__((ext_vector_type(8)));   // 8 bf16 = 4 VGPRs
typedef float floatx16 __attribute__((ext_vector_type(16)));

// Convert 8 contiguous fp32 -> bf16x8 (RNE), accumulating sum of squares of
// the ROUNDED values (so d2 = xsq+ysq-2*cross is the exact squared distance
// of the bf16 vectors, >= 0 up to fp32 roundoff).
__device__ __forceinline__ bf16x8 cvt8(const float* __restrict__ p, float& ss) {
    const float4 a = *(const float4*)p;
    const float4 b = *(const float4*)(p + 4);
    const float f[8] = {a.x, a.y, a.z, a.w, b.x, b.y, b.z, b.w};
    bf16x8 r;
#pragma unroll
    for (int i = 0; i < 8; ++i) {
        __hip_bfloat16 h = __float2bfloat16(f[i]);
        short s;
        memcpy(&s, &h, sizeof(short));
        r[i] = s;
        const float bv = __bfloat162float(h);
        ss = fmaf(bv, bv, ss);
    }
    return r;
}

// ---------------------------------------------------------------------------
// Single prep pass over BOTH matrices: fp32 [rows,64] -> bf16 [rows,64] +
// fp32 row norms of the rounded values. One thread per 8 elements (16B
// load/8B... 32B loads, 16B stores); 8 lanes per row, shfl_xor reduce.
// Rows [0,nA) come from srcA, rows [nA,nTot) from srcB. nA is a multiple of
// 32 in the fast path, so no wave straddles the A/B boundary.
// ---------------------------------------------------------------------------
__global__ __launch_bounds__(256) void prep_all(const float* __restrict__ srcA,
                                                const float* __restrict__ srcB,
                                                short* __restrict__ dstA,
                                                short* __restrict__ dstB,
                                                float* __restrict__ nrmA,
                                                float* __restrict__ nrmB,
                                                int nA, int nTot) {
    const int idx = blockIdx.x * 256 + threadIdx.x;
    const int row = idx >> 3;
    const int sub = idx & 7;
    if (row >= nTot) return;
    const float* src;
    short* dst;
    float* nrm;
    int r;
    if (row < nA) { src = srcA; dst = dstA; nrm = nrmA; r = row; }
    else          { src = srcB; dst = dstB; nrm = nrmB; r = row - nA; }
    float ss = 0.f;
    const bf16x8 v = cvt8(src + (size_t)r * D + sub * 8, ss);
    *(bf16x8*)(dst + (size_t)r * D + sub * 8) = v;
    ss += __shfl_xor(ss, 1, 64);
    ss += __shfl_xor(ss, 2, 64);
    ss += __shfl_xor(ss, 4, 64);
    if (sub == 0) nrm[r] = ss;
}

// ---------------------------------------------------------------------------
// RBF GEMM, 32x32x16 MFMA. Block = 128 rows x 256 cols (CT=2 tiles of 128),
// 4 waves in 2x2 per tile; each wave owns 64x64 = 2x2 of 32x32 MFMAs, K=64
// in 4 steps. Fragments read straight from the bf16 staging buffers
// (row-major, K contiguous): lane holds row/col = lane&31,
// k = (lane>>5)*8 + j -> one 16B load per ks. [HW-verified: round-4 pass]
// C/D layout: col = lane&31, row = (rg&3) + 8*(rg>>2) + 4*(lane>>5)
// -> each store instruction writes 2 full aligned 128B lines (nontemporal:
// the 268MB output stream shouldn't thrash L2's cached bf16 panels).
// B-row norm is lane-local in the epilogue (col == lane&31 == norm lane).
// ---------------------------------------------------------------------------
__global__ __launch_bounds__(256) void rbf_gemm32(const short* __restrict__ A,
                                                  const short* __restrict__ B,
                                                  const float* __restrict__ xsq,
                                                  const float* __restrict__ ysq,
                                                  float* __restrict__ out,
                                                  int M) {
    const int wid  = threadIdx.x >> 6;
    const int lane = threadIdx.x & 63;
    const int r32  = lane & 31;
    const int h    = lane >> 5;

    const long row0 = (long)blockIdx.y * 128 + (wid >> 1) * 64;
    const long colW = (long)blockIdx.x * (128 * CT) + (wid & 1) * 64;

    // A fragments + row norms: once per block, reused for CT column tiles.
    bf16x8 af[2][4];
    float xn_l[2];   // norm of A row (row0 + mb*32 + r32), replicated over h
#pragma unroll
    for (int mb = 0; mb < 2; ++mb) {
        const short* p = A + (row0 + mb * 32 + r32) * D + h * 8;
#pragma unroll
        for (int ks = 0; ks < 4; ++ks)
            af[mb][ks] = *(const bf16x8*)(p + ks * 16);   // k = ks*16 + h*8 + [0,8)
        xn_l[mb] = xsq[row0 + mb * 32 + r32];
    }

    for (int ct = 0; ct < CT; ++ct) {
        const long colT = colW + (long)ct * 128;

        bf16x8 bfr[2][4];
        float yn_l[2];
#pragma unroll
        for (int nb = 0; nb < 2; ++nb) {
            const short* p = B + (colT + nb * 32 + r32) * D + h * 8;
#pragma unroll
            for (int ks = 0; ks < 4; ++ks)
                bfr[nb][ks] = *(const bf16x8*)(p + ks * 16);
            yn_l[nb] = ysq[colT + nb * 32 + r32];
        }

        floatx16 acc[2][2] = {};
#pragma unroll
        for (int ks = 0; ks < 4; ++ks)
#pragma unroll
            for (int mb = 0; mb < 2; ++mb)
#pragma unroll
                for (int nb = 0; nb < 2; ++nb)
                    acc[mb][nb] = __builtin_amdgcn_mfma_f32_32x32x16_bf16(
                        af[mb][ks], bfr[nb][ks], acc[mb][nb], 0, 0, 0);

        // Epilogue: d2 = xsq+ysq-2*cross (clamped), out = exp(-gamma*d2).
#pragma unroll
        for (int mb = 0; mb < 2; ++mb) {
            float xnv[16];
#pragma unroll
            for (int rg = 0; rg < 16; ++rg)
                xnv[rg] = __shfl(xn_l[mb], (rg & 3) + 8 * (rg >> 2) + 4 * h, 64);
#pragma unroll
            for (int nb = 0; nb < 2; ++nb) {
                const float yn = yn_l[nb];
                float* op = out + (row0 + mb * 32) * (long)M + colT + nb * 32 + r32;
#pragma unroll
                for (int rg = 0; rg < 16; ++rg) {
                    const int rl = (rg & 3) + 8 * (rg >> 2) + 4 * h;
                    const float d2 = fmaxf(xnv[rg] + yn - 2.0f * acc[mb][nb][rg], 0.0f);
                    __builtin_nontemporal_store(__expf(-GAMMA * d2), op + (long)rl * M);
                }
            }
        }
    }
}

// ---------------------------------------------------------------------------
// Fallback (dims not multiples of the tile, or tiny workspace): direct fp32.
// ---------------------------------------------------------------------------
__global__ __launch_bounds__(256) void rbf_naive(const float* __restrict__ X,
                                                 const float* __restrict__ Y,
                                                 float* __restrict__ out,
                                                 int N, int M) {
    long idx = (long)blockIdx.x * blockDim.x + threadIdx.x;
    if (idx >= (long)N * M) return;
    long i = idx / M, j = idx % M;
    float s = 0.0f;
#pragma unroll
    for (int k = 0; k < D; ++k) {
        float d = X[i * D + k] - Y[j * D + k];
        s = fmaf(d, d, s);
    }
    out[idx] = __expf(-GAMMA * s);
}

extern "C" void kernel_launch(void* const* d_in, const int* in_sizes, int n_in,
                              void* d_out, int out_size, void* d_ws, size_t ws_size,
                              hipStream_t stream) {
    const float* data = (const float*)d_in[0];
    const float* sv   = (const float*)d_in[1];
    float* out = (float*)d_out;
    // NOTE: in_sizes is in ELEMENTS (fp32 count), not bytes: 8192*64 = 524288.
    const int N = in_sizes[0] / D;   // rows of data
    const int M = in_sizes[1] / D;   // rows of sv

    const size_t bfA  = (size_t)N * D * sizeof(short);
    const size_t bfB  = (size_t)M * D * sizeof(short);
    const size_t need = bfA + bfB + (size_t)(N + M) * sizeof(float);

    if (ws_size >= need && (N % 128) == 0 && (M % (128 * CT)) == 0) {
        char* ws = (char*)d_ws;
        short* Abf = (short*)ws;
        short* Bbf = (short*)(ws + bfA);
        float* xsq = (float*)(ws + bfA + bfB);
        float* ysq = xsq + N;

        const int nTot = N + M;
        const int prep_blocks = (nTot * 8 + 255) / 256;
        hipLaunchKernelGGL(prep_all, dim3(prep_blocks), dim3(256), 0, stream,
                           data, sv, Abf, Bbf, xsq, ysq, N, nTot);
        dim3 grid(M / (128 * CT), N / 128);
        hipLaunchKernelGGL(rbf_gemm32, grid, dim3(256), 0, stream,
                           Abf, Bbf, xsq, ysq, out, M);
    } else {
        long total = (long)N * M;
        long blocks = (total + 255) / 256;
        hipLaunchKernelGGL(rbf_naive, dim3((unsigned)blocks), dim3(256), 0, stream,
                           data, sv, out, N, M);
    }
}